// Round 21
// baseline (277.737 us; speedup 1.0000x reference)
//
#include <hip/hip_runtime.h>
#include <hip/hip_bf16.h>
#include <cstdint>
#include <cstddef>

// ---------------------------------------------------------------------------
// SwinWindowTransformLayer: roll+add -> LayerNorm -> MLP(GELU) -> +x
// Round 21: single variable — G1 __launch_bounds__(256,5) (5 blocks/CU,
// LDS-max occupancy; VGPR cap 96 >= 84 used). Everything else frozen
// from R20 (prep fusion + corrected G2 swizzle).
// ---------------------------------------------------------------------------

typedef short bf16x8 __attribute__((ext_vector_type(8)));
typedef float f32x4 __attribute__((ext_vector_type(4)));

#define GLOBAL_AS(p) ((__attribute__((address_space(1))) void*)(uintptr_t)(p))
#define LDS_AS(p)    ((__attribute__((address_space(3))) void*)(p))

static __device__ __forceinline__ ushort f2bf(float f) {
    uint32_t u = __float_as_uint(f);
    uint32_t r = (u + 0x7FFFu + ((u >> 16) & 1u)) >> 16;
    return (ushort)r;
}

// tanh-gelu == v*sigmoid(v*(A+B v^2)); exp via v_exp_f32 (2^x), log2e folded.
static __device__ __forceinline__ float gelu_e2(float v) {
    float v2 = v * v;
    float m = fmaf(-0.1029433f, v2, -2.3022084f);
    float t = v * m;
    float e;
    asm("v_exp_f32 %0, %1" : "=v"(e) : "v"(t));
    return v * __builtin_amdgcn_rcpf(1.0f + e);
}

// roll by (-4,-4) on a 64x64 grid
static __device__ __forceinline__ int rolled_row(int row) {
    int b = row >> 12, n = row & 4095;
    int h = n >> 6, wv = n & 63;
    int n2 = (((h + 4) & 63) << 6) | ((wv + 4) & 63);
    return (b << 12) | n2;
}

#define SBAR() do { __builtin_amdgcn_sched_barrier(0); \
                    __builtin_amdgcn_s_barrier(); \
                    __builtin_amdgcn_sched_barrier(0); } while (0)

#define LBAR() do { __builtin_amdgcn_sched_barrier(0); \
                    asm volatile("s_waitcnt lgkmcnt(0)" ::: "memory"); \
                    __builtin_amdgcn_s_barrier(); \
                    __builtin_amdgcn_sched_barrier(0); } while (0)

// ---------------------------------------------------------------------------
// prep: blockIdx [0,16384) = LN (2 rows/block); [16384,17408) = W1 transpose;
// [17408,18432) = W2 transpose (k-permuted). 256 threads everywhere.
// ---------------------------------------------------------------------------
__global__ __launch_bounds__(256)
void prep_kernel(const float* __restrict__ in, const float* __restrict__ gamma,
                 const float* __restrict__ beta, ushort* __restrict__ normed,
                 const float* __restrict__ W1, ushort* __restrict__ W1T,
                 const float* __restrict__ W2, ushort* __restrict__ W2T) {
    const int bid = blockIdx.x;
    if (bid < 16384) {
        const int half = threadIdx.x >> 7;
        const int t = threadIdx.x & 127;
        const int wave = threadIdx.x >> 6;
        const int row = bid * 2 + half;
        const int row2 = rolled_row(row);

        const float4* p0 = (const float4*)(in + (size_t)row * 512);
        const float4* p1 = (const float4*)(in + (size_t)row2 * 512);
        float4 a = p0[t], c = p1[t];
        float x0 = a.x + c.x, x1 = a.y + c.y, x2 = a.z + c.z, x3 = a.w + c.w;

        float s = x0 + x1 + x2 + x3;
        float sq = x0 * x0 + x1 * x1 + x2 * x2 + x3 * x3;
#pragma unroll
        for (int o = 32; o > 0; o >>= 1) {
            s += __shfl_xor(s, o);
            sq += __shfl_xor(sq, o);
        }
        __shared__ float red[4][2];
        if ((threadIdx.x & 63) == 0) { red[wave][0] = s; red[wave][1] = sq; }
        __syncthreads();
        const int w0 = half * 2;
        s = red[w0][0] + red[w0 + 1][0];
        sq = red[w0][1] + red[w0 + 1][1];
        float mu = s * (1.0f / 512.0f);
        float var = sq * (1.0f / 512.0f) - mu * mu;
        float rs = rsqrtf(var + 1e-6f);

        float4 g = ((const float4*)gamma)[t];
        float4 be = ((const float4*)beta)[t];
        ushort4 o4;
        o4.x = f2bf((x0 - mu) * rs * g.x + be.x);
        o4.y = f2bf((x1 - mu) * rs * g.y + be.y);
        o4.z = f2bf((x2 - mu) * rs * g.z + be.z);
        o4.w = f2bf((x3 - mu) * rs * g.w + be.w);
        ((ushort4*)(normed + (size_t)row * 512))[t] = o4;
    } else {
        __shared__ float tile[32][33];
        const int tx = threadIdx.x & 31, ty = threadIdx.x >> 5;
        const bool isW2 = bid >= 17408;
        const int i = isW2 ? (bid - 17408) : (bid - 16384);
        const int NBX = isW2 ? 16 : 64;
        const int Ccols = isW2 ? 512 : 2048;
        const int R = isW2 ? 2048 : 512;
        const float* src = isW2 ? W2 : W1;
        ushort* dst = isW2 ? W2T : W1T;
        const int bx = (i % NBX) * 32;
        const int by = (i / NBX) * 32;
#pragma unroll
        for (int r = 0; r < 32; r += 8)
            tile[ty + r][tx] = src[(size_t)(by + ty + r) * Ccols + bx + tx];
        __syncthreads();
        int k = by + tx;
        int kd = isW2 ? ((k & ~63) | ((k & 15) << 2) | ((k >> 4) & 3)) : k;
#pragma unroll
        for (int r = 0; r < 32; r += 8)
            dst[(size_t)(bx + ty + r) * R + kd] = f2bf(tile[tx][ty + r]);
    }
}

// ---------------------------------------------------------------------------
// G1: h = bf16(gelu(normed @ W1 + b1)), k-permuted stores. 128x128 tile,
// BK=64, 2-barrier K-loop, conflict-free XOR swizzle, XCD row-panel order.
// (256,5): 5 blocks/CU (LDS max); VGPR cap 96 >= 84 used.
// ---------------------------------------------------------------------------
__global__ __launch_bounds__(256, 5)
void mlp_gemm1(const ushort* __restrict__ A, const ushort* __restrict__ Bt,
               const float* __restrict__ bias, ushort* __restrict__ outH) {
    constexpr int K = 512, N = 2048, BK = 64;
    __shared__ ushort Asm[128 * BK];   // 16 KB
    __shared__ ushort Bsm[128 * BK];   // 16 KB

    const int t = threadIdx.x;
    const int w = t >> 6, l = t & 63;
    const int wr = w >> 1, wc = w & 1;

    const int bid = blockIdx.x;
    const int xcd = bid & 7, idx = bid >> 3;
    const int brow = ((xcd << 5) + (idx >> 4)) << 7;
    const int bcol = (idx & 15) << 7;

    f32x4 acc[4][4] = {};

    const int trow = t >> 3;
    const int csrc = (((t & 7) ^ ((t >> 3) & 7)) << 3);
    const size_t aBase = (size_t)(brow + trow) * K + csrc;
    const size_t bBase = (size_t)(bcol + trow) * K + csrc;
    char* const ldsA = (char*)Asm + w * 1024;
    char* const ldsB = (char*)Bsm + w * 1024;

    const int rA = l & 15;
    const int cb0 = ((l >> 4) ^ (rA & 7)) << 4;
    const int bA0 = (wr << 13) + (rA << 7) + cb0;
    const int bB0 = (wc << 13) + (rA << 7) + cb0;
    const char* const pA0 = (const char*)Asm + bA0;
    const char* const pA1 = (const char*)Asm + (bA0 ^ 64);
    const char* const pB0 = (const char*)Bsm + bB0;
    const char* const pB1 = (const char*)Bsm + (bB0 ^ 64);

    for (int k0 = 0; k0 < K; k0 += BK) {
#pragma unroll
        for (int i = 0; i < 4; ++i) {
            __builtin_amdgcn_global_load_lds(GLOBAL_AS(A + aBase + (size_t)(i * 32) * K + k0),
                                             LDS_AS(ldsA + i * 4096), 16, 0, 0);
            __builtin_amdgcn_global_load_lds(GLOBAL_AS(Bt + bBase + (size_t)(i * 32) * K + k0),
                                             LDS_AS(ldsB + i * 4096), 16, 0, 0);
        }
        __syncthreads();

#pragma unroll
        for (int s = 0; s < 2; ++s) {
            const char* pa = s ? pA1 : pA0;
            const char* pb = s ? pB1 : pB0;
            bf16x8 aF[4], bF[4];
#pragma unroll
            for (int i = 0; i < 4; ++i)
                aF[i] = *(const bf16x8*)(pa + i * 2048);
#pragma unroll
            for (int j = 0; j < 4; ++j)
                bF[j] = *(const bf16x8*)(pb + j * 2048);
#pragma unroll
            for (int i = 0; i < 4; ++i)
#pragma unroll
                for (int j = 0; j < 4; ++j)
                    acc[i][j] = __builtin_amdgcn_mfma_f32_16x16x32_bf16(aF[i], bF[j], acc[i][j], 0, 0, 0);
        }
        __syncthreads();
    }

    const int cm = (l >> 4) << 2;
    const int cn = l & 15;
    float bvv[4];
#pragma unroll
    for (int j = 0; j < 4; ++j)
        bvv[j] = bias[bcol + wc * 64 + j * 16 + cn];
    const int ecol = bcol + wc * 64 + (cn << 2);
#pragma unroll
    for (int i = 0; i < 4; ++i) {
#pragma unroll
        for (int r = 0; r < 4; ++r) {
            const int row = brow + wr * 64 + i * 16 + cm + r;
            float f0 = gelu_e2(acc[i][0][r] + bvv[0]);
            float f1 = gelu_e2(acc[i][1][r] + bvv[1]);
            float f2 = gelu_e2(acc[i][2][r] + bvv[2]);
            float f3 = gelu_e2(acc[i][3][r] + bvv[3]);
            uint32_t lo, hi;
            asm("v_cvt_pk_bf16_f32 %0, %1, %2" : "=v"(lo) : "v"(f0), "v"(f1));
            asm("v_cvt_pk_bf16_f32 %0, %1, %2" : "=v"(hi) : "v"(f2), "v"(f3));
            uint2 pv; pv.x = lo; pv.y = hi;
            *(uint2*)(outH + (size_t)row * N + ecol) = pv;
        }
    }
}

// ---------------------------------------------------------------------------
// G2 (frozen from R19/R20): out = hbuf @ W2 + b2 + resid[row]+resid[roll].
// 8-phase 256x256 loop (KT=2048, TT=32), corrected 8-lane-group swizzle.
// ---------------------------------------------------------------------------
__global__ __launch_bounds__(512, 2)
void mlp_gemm2(const ushort* __restrict__ A, const ushort* __restrict__ Bt,
               const float* __restrict__ bias, const float* __restrict__ resid,
               float* __restrict__ outF) {
    constexpr int KT = 2048, TT = 32, N = 512;
    __shared__ __align__(16) char sm[131072];
    const int t = threadIdx.x;
    const int w = t >> 6, l = t & 63;
    const int wr = w >> 2, wc = w & 3;

    const int nwg = gridDim.x;
    const int bid = blockIdx.x;
    const int swz = (bid & 7) * (nwg >> 3) + (bid >> 3);
    const int cb = swz & 1;
    const int rgrp = swz >> 1;
    const int brow0 = rgrp * 256;
    const int bcol = cb << 8;

    const int kksw = (((t & 3) ^ ((t >> 3) & 3)) << 3);
    const size_t aTh = (size_t)(t >> 2) * KT + kksw;
    const size_t bTh = (size_t)(bcol + (t >> 2)) * KT + kksw;
    const ushort* const aPanel = A + (size_t)brow0 * KT;
    char* const dA = (char*)sm + (w << 10);
    char* const dB = dA + 65536;

    const int xorv = ((l >> 1) & 3) << 4;
    const int preA = ((((wr << 7) + (l & 15)) << 6) + ((l >> 4) << 4)) ^ xorv;
    const int preB = 65536 + (((((wc << 6) + (l & 15)) << 6) + ((l >> 4) << 4)) ^ xorv);

    f32x4 acc[8][4] = {};
    bf16x8 aF[4], bF[4];

    auto issueA = [&](int T, int kh) {
        const int slot = ((T & 1) << 1) | kh;
        const ushort* s = aPanel + aTh + T * 64 + kh * 32;
        char* d = dA + (slot << 14);
        __builtin_amdgcn_global_load_lds(GLOBAL_AS(s), LDS_AS(d), 16, 0, 0);
        __builtin_amdgcn_global_load_lds(GLOBAL_AS(s + (size_t)128 * KT), LDS_AS(d + 8192), 16, 0, 0);
    };
    auto issueB = [&](int T, int kh) {
        const int slot = ((T & 1) << 1) | kh;
        const ushort* s = Bt + bTh + T * 64 + kh * 32;
        char* d = dB + (slot << 14);
        __builtin_amdgcn_global_load_lds(GLOBAL_AS(s), LDS_AS(d), 16, 0, 0);
        __builtin_amdgcn_global_load_lds(GLOBAL_AS(s + (size_t)128 * KT), LDS_AS(d + 8192), 16, 0, 0);
    };
    auto rdA = [&](int slot, int mb) {
        const char* p = (const char*)sm + (slot << 14) + preA + (mb << 12);
        aF[0] = *(const bf16x8*)(p);
        aF[1] = *(const bf16x8*)(p + 1024);
        aF[2] = *(const bf16x8*)(p + 2048);
        aF[3] = *(const bf16x8*)(p + 3072);
    };
    auto rdB = [&](int slot) {
        const char* p = (const char*)sm + (slot << 14) + preB;
        bF[0] = *(const bf16x8*)(p);
        bF[1] = *(const bf16x8*)(p + 1024);
        bF[2] = *(const bf16x8*)(p + 2048);
        bF[3] = *(const bf16x8*)(p + 3072);
    };
    auto mfma16 = [&](int mb) {
        __builtin_amdgcn_s_setprio(1);
#pragma unroll
        for (int mf = 0; mf < 4; ++mf)
#pragma unroll
            for (int nf = 0; nf < 4; ++nf)
                acc[mb * 4 + mf][nf] = __builtin_amdgcn_mfma_f32_16x16x32_bf16(
                    aF[mf], bF[nf], acc[mb * 4 + mf][nf], 0, 0, 0);
        __builtin_amdgcn_s_setprio(0);
    };

    auto tile_body = [&](int T) {
        const int s0 = (T & 1) << 1;
        rdA(s0, 0); rdB(s0);
        if (T + 1 < TT) issueB(T + 1, 1);
        SBAR();
        mfma16(0);
        SBAR();
        rdA(s0, 1);
        if (T + 2 < TT) issueA(T + 2, 0);
        SBAR();
        mfma16(1);
        SBAR();
        rdA(s0 + 1, 0); rdB(s0 + 1);
        if (T + 2 < TT) issueB(T + 2, 0);
        SBAR();
        mfma16(0);
        SBAR();
        rdA(s0 + 1, 1);
        if (T + 2 < TT) issueA(T + 2, 1);
        SBAR();
        mfma16(1);
        __builtin_amdgcn_sched_barrier(0);
        if (T < TT - 2)       { asm volatile("s_waitcnt vmcnt(6)" ::: "memory"); }
        else if (T == TT - 2) { asm volatile("s_waitcnt vmcnt(0)" ::: "memory"); }
        SBAR();
    };

    issueA(0, 0); issueB(0, 0);
    issueA(0, 1); issueB(0, 1);
    issueA(1, 0); issueB(1, 0);
    issueA(1, 1);
    __builtin_amdgcn_sched_barrier(0);
    asm volatile("s_waitcnt vmcnt(6)" ::: "memory");
    SBAR();

#pragma unroll 1
    for (int T = 0; T < TT; ++T)
        tile_body(T);

    // epilogue: two 128-row f32 [128][256] LDS halves (lgkm-only barriers).
#pragma unroll
    for (int h2 = 0; h2 < 2; ++h2) {
        if (wr == h2) {
#pragma unroll
            for (int mf = 0; mf < 8; ++mf)
#pragma unroll
                for (int nf = 0; nf < 4; ++nf)
#pragma unroll
                    for (int r = 0; r < 4; ++r) {
                        int rl = mf * 16 + ((l >> 4) << 2) + r;
                        int col = (wc << 6) + nf * 16 + (l & 15);
                        *(float*)(sm + rl * 1024 + col * 4) = acc[mf][nf][r];
                    }
        }
        LBAR();
#pragma unroll
        for (int k = 0; k < 16; ++k) {
            int c = t + (k << 9);
            int row = c >> 6, c4 = c & 63;
            f32x4 v = *(const f32x4*)(sm + ((size_t)c << 4));
            int R = brow0 + (h2 << 7) + row;
            int col0 = bcol + (c4 << 2);
            f32x4 bb = *(const f32x4*)(bias + col0);
            f32x4 x0 = *(const f32x4*)(resid + (size_t)R * 512 + col0);
            f32x4 x1 = *(const f32x4*)(resid + (size_t)rolled_row(R) * 512 + col0);
            v = v + bb + x0 + x1;
            *(f32x4*)(outF + (size_t)R * N + col0) = v;
        }
        if (h2 == 0) LBAR();
    }
}

// ---------------------------------------------------------------------------
extern "C" void kernel_launch(void* const* d_in, const int* in_sizes, int n_in,
                              void* d_out, int out_size, void* d_ws, size_t ws_size,
                              hipStream_t stream) {
    const float* in = (const float*)d_in[0];
    const float* ln_g = (const float*)d_in[1];
    const float* ln_b = (const float*)d_in[2];
    const float* W1 = (const float*)d_in[3];
    const float* b1 = (const float*)d_in[4];
    const float* W2 = (const float*)d_in[5];
    const float* b2 = (const float*)d_in[6];
    float* out = (float*)d_out;

    char* ws = (char*)d_ws;
    ushort* normed = (ushort*)ws;                                  // 32 MB
    ushort* hbuf   = (ushort*)(ws + (size_t)32 * 1024 * 1024);     // 128 MB (k-permuted)
    ushort* W1T    = (ushort*)(ws + (size_t)160 * 1024 * 1024);    // 2 MB
    ushort* W2T    = (ushort*)(ws + (size_t)162 * 1024 * 1024);    // 2 MB (k-permuted)

    prep_kernel<<<dim3(18432), 256, 0, stream>>>(in, ln_g, ln_b, normed,
                                                 W1, W1T, W2, W2T);
    mlp_gemm1<<<dim3(4096), 256, 0, stream>>>(normed, W1T, b1, hbuf);
    mlp_gemm2<<<dim3(256), 512, 0, stream>>>(hbuf, W2T, b2, in, out);
}

// Round 22
// 192.499 us; speedup vs baseline: 1.4428x; 1.4428x over previous
//
#include <hip/hip_runtime.h>
#include <hip/hip_bf16.h>
#include <cstdint>
#include <cstddef>

// ---------------------------------------------------------------------------
// SwinWindowTransformLayer: roll+add -> LayerNorm -> MLP(GELU) -> +x
// Round 22: exact revert to R20 (best, 191.6 us). R21's (256,5) capped
// VGPRs at 48 -> accumulator spills (WRITE 450 MB, G1 172 us). G1 stays at
// (256,4): 4 blocks/CU is the register-file-feasible occupancy maximum.
// ---------------------------------------------------------------------------

typedef short bf16x8 __attribute__((ext_vector_type(8)));
typedef float f32x4 __attribute__((ext_vector_type(4)));

#define GLOBAL_AS(p) ((__attribute__((address_space(1))) void*)(uintptr_t)(p))
#define LDS_AS(p)    ((__attribute__((address_space(3))) void*)(p))

static __device__ __forceinline__ ushort f2bf(float f) {
    uint32_t u = __float_as_uint(f);
    uint32_t r = (u + 0x7FFFu + ((u >> 16) & 1u)) >> 16;
    return (ushort)r;
}

// tanh-gelu == v*sigmoid(v*(A+B v^2)); exp via v_exp_f32 (2^x), log2e folded.
static __device__ __forceinline__ float gelu_e2(float v) {
    float v2 = v * v;
    float m = fmaf(-0.1029433f, v2, -2.3022084f);
    float t = v * m;
    float e;
    asm("v_exp_f32 %0, %1" : "=v"(e) : "v"(t));
    return v * __builtin_amdgcn_rcpf(1.0f + e);
}

// roll by (-4,-4) on a 64x64 grid
static __device__ __forceinline__ int rolled_row(int row) {
    int b = row >> 12, n = row & 4095;
    int h = n >> 6, wv = n & 63;
    int n2 = (((h + 4) & 63) << 6) | ((wv + 4) & 63);
    return (b << 12) | n2;
}

#define SBAR() do { __builtin_amdgcn_sched_barrier(0); \
                    __builtin_amdgcn_s_barrier(); \
                    __builtin_amdgcn_sched_barrier(0); } while (0)

#define LBAR() do { __builtin_amdgcn_sched_barrier(0); \
                    asm volatile("s_waitcnt lgkmcnt(0)" ::: "memory"); \
                    __builtin_amdgcn_s_barrier(); \
                    __builtin_amdgcn_sched_barrier(0); } while (0)

// ---------------------------------------------------------------------------
// prep: blockIdx [0,16384) = LN (2 rows/block); [16384,17408) = W1 transpose;
// [17408,18432) = W2 transpose (k-permuted). 256 threads everywhere.
// ---------------------------------------------------------------------------
__global__ __launch_bounds__(256)
void prep_kernel(const float* __restrict__ in, const float* __restrict__ gamma,
                 const float* __restrict__ beta, ushort* __restrict__ normed,
                 const float* __restrict__ W1, ushort* __restrict__ W1T,
                 const float* __restrict__ W2, ushort* __restrict__ W2T) {
    const int bid = blockIdx.x;
    if (bid < 16384) {
        const int half = threadIdx.x >> 7;
        const int t = threadIdx.x & 127;
        const int wave = threadIdx.x >> 6;
        const int row = bid * 2 + half;
        const int row2 = rolled_row(row);

        const float4* p0 = (const float4*)(in + (size_t)row * 512);
        const float4* p1 = (const float4*)(in + (size_t)row2 * 512);
        float4 a = p0[t], c = p1[t];
        float x0 = a.x + c.x, x1 = a.y + c.y, x2 = a.z + c.z, x3 = a.w + c.w;

        float s = x0 + x1 + x2 + x3;
        float sq = x0 * x0 + x1 * x1 + x2 * x2 + x3 * x3;
#pragma unroll
        for (int o = 32; o > 0; o >>= 1) {
            s += __shfl_xor(s, o);
            sq += __shfl_xor(sq, o);
        }
        __shared__ float red[4][2];
        if ((threadIdx.x & 63) == 0) { red[wave][0] = s; red[wave][1] = sq; }
        __syncthreads();
        const int w0 = half * 2;
        s = red[w0][0] + red[w0 + 1][0];
        sq = red[w0][1] + red[w0 + 1][1];
        float mu = s * (1.0f / 512.0f);
        float var = sq * (1.0f / 512.0f) - mu * mu;
        float rs = rsqrtf(var + 1e-6f);

        float4 g = ((const float4*)gamma)[t];
        float4 be = ((const float4*)beta)[t];
        ushort4 o4;
        o4.x = f2bf((x0 - mu) * rs * g.x + be.x);
        o4.y = f2bf((x1 - mu) * rs * g.y + be.y);
        o4.z = f2bf((x2 - mu) * rs * g.z + be.z);
        o4.w = f2bf((x3 - mu) * rs * g.w + be.w);
        ((ushort4*)(normed + (size_t)row * 512))[t] = o4;
    } else {
        __shared__ float tile[32][33];
        const int tx = threadIdx.x & 31, ty = threadIdx.x >> 5;
        const bool isW2 = bid >= 17408;
        const int i = isW2 ? (bid - 17408) : (bid - 16384);
        const int NBX = isW2 ? 16 : 64;
        const int Ccols = isW2 ? 512 : 2048;
        const int R = isW2 ? 2048 : 512;
        const float* src = isW2 ? W2 : W1;
        ushort* dst = isW2 ? W2T : W1T;
        const int bx = (i % NBX) * 32;
        const int by = (i / NBX) * 32;
#pragma unroll
        for (int r = 0; r < 32; r += 8)
            tile[ty + r][tx] = src[(size_t)(by + ty + r) * Ccols + bx + tx];
        __syncthreads();
        int k = by + tx;
        int kd = isW2 ? ((k & ~63) | ((k & 15) << 2) | ((k >> 4) & 3)) : k;
#pragma unroll
        for (int r = 0; r < 32; r += 8)
            dst[(size_t)(bx + ty + r) * R + kd] = f2bf(tile[tx][ty + r]);
    }
}

// ---------------------------------------------------------------------------
// G1: h = bf16(gelu(normed @ W1 + b1)), k-permuted stores. 128x128 tile,
// BK=64, 2-barrier K-loop, conflict-free XOR swizzle, XCD row-panel order.
// (256,4): 4 blocks/CU — register-file-feasible max (5 spills: R21).
// ---------------------------------------------------------------------------
__global__ __launch_bounds__(256, 4)
void mlp_gemm1(const ushort* __restrict__ A, const ushort* __restrict__ Bt,
               const float* __restrict__ bias, ushort* __restrict__ outH) {
    constexpr int K = 512, N = 2048, BK = 64;
    __shared__ ushort Asm[128 * BK];   // 16 KB
    __shared__ ushort Bsm[128 * BK];   // 16 KB

    const int t = threadIdx.x;
    const int w = t >> 6, l = t & 63;
    const int wr = w >> 1, wc = w & 1;

    const int bid = blockIdx.x;
    const int xcd = bid & 7, idx = bid >> 3;
    const int brow = ((xcd << 5) + (idx >> 4)) << 7;
    const int bcol = (idx & 15) << 7;

    f32x4 acc[4][4] = {};

    const int trow = t >> 3;
    const int csrc = (((t & 7) ^ ((t >> 3) & 7)) << 3);
    const size_t aBase = (size_t)(brow + trow) * K + csrc;
    const size_t bBase = (size_t)(bcol + trow) * K + csrc;
    char* const ldsA = (char*)Asm + w * 1024;
    char* const ldsB = (char*)Bsm + w * 1024;

    const int rA = l & 15;
    const int cb0 = ((l >> 4) ^ (rA & 7)) << 4;
    const int bA0 = (wr << 13) + (rA << 7) + cb0;
    const int bB0 = (wc << 13) + (rA << 7) + cb0;
    const char* const pA0 = (const char*)Asm + bA0;
    const char* const pA1 = (const char*)Asm + (bA0 ^ 64);
    const char* const pB0 = (const char*)Bsm + bB0;
    const char* const pB1 = (const char*)Bsm + (bB0 ^ 64);

    for (int k0 = 0; k0 < K; k0 += BK) {
#pragma unroll
        for (int i = 0; i < 4; ++i) {
            __builtin_amdgcn_global_load_lds(GLOBAL_AS(A + aBase + (size_t)(i * 32) * K + k0),
                                             LDS_AS(ldsA + i * 4096), 16, 0, 0);
            __builtin_amdgcn_global_load_lds(GLOBAL_AS(Bt + bBase + (size_t)(i * 32) * K + k0),
                                             LDS_AS(ldsB + i * 4096), 16, 0, 0);
        }
        __syncthreads();

#pragma unroll
        for (int s = 0; s < 2; ++s) {
            const char* pa = s ? pA1 : pA0;
            const char* pb = s ? pB1 : pB0;
            bf16x8 aF[4], bF[4];
#pragma unroll
            for (int i = 0; i < 4; ++i)
                aF[i] = *(const bf16x8*)(pa + i * 2048);
#pragma unroll
            for (int j = 0; j < 4; ++j)
                bF[j] = *(const bf16x8*)(pb + j * 2048);
#pragma unroll
            for (int i = 0; i < 4; ++i)
#pragma unroll
                for (int j = 0; j < 4; ++j)
                    acc[i][j] = __builtin_amdgcn_mfma_f32_16x16x32_bf16(aF[i], bF[j], acc[i][j], 0, 0, 0);
        }
        __syncthreads();
    }

    const int cm = (l >> 4) << 2;
    const int cn = l & 15;
    float bvv[4];
#pragma unroll
    for (int j = 0; j < 4; ++j)
        bvv[j] = bias[bcol + wc * 64 + j * 16 + cn];
    const int ecol = bcol + wc * 64 + (cn << 2);
#pragma unroll
    for (int i = 0; i < 4; ++i) {
#pragma unroll
        for (int r = 0; r < 4; ++r) {
            const int row = brow + wr * 64 + i * 16 + cm + r;
            float f0 = gelu_e2(acc[i][0][r] + bvv[0]);
            float f1 = gelu_e2(acc[i][1][r] + bvv[1]);
            float f2 = gelu_e2(acc[i][2][r] + bvv[2]);
            float f3 = gelu_e2(acc[i][3][r] + bvv[3]);
            uint32_t lo, hi;
            asm("v_cvt_pk_bf16_f32 %0, %1, %2" : "=v"(lo) : "v"(f0), "v"(f1));
            asm("v_cvt_pk_bf16_f32 %0, %1, %2" : "=v"(hi) : "v"(f2), "v"(f3));
            uint2 pv; pv.x = lo; pv.y = hi;
            *(uint2*)(outH + (size_t)row * N + ecol) = pv;
        }
    }
}

// ---------------------------------------------------------------------------
// G2 (frozen): out = hbuf @ W2 + b2 + resid[row] + resid[roll(row)].
// 8-phase 256x256 loop (KT=2048, TT=32), corrected 8-lane-group swizzle.
// ---------------------------------------------------------------------------
__global__ __launch_bounds__(512, 2)
void mlp_gemm2(const ushort* __restrict__ A, const ushort* __restrict__ Bt,
               const float* __restrict__ bias, const float* __restrict__ resid,
               float* __restrict__ outF) {
    constexpr int KT = 2048, TT = 32, N = 512;
    __shared__ __align__(16) char sm[131072];
    const int t = threadIdx.x;
    const int w = t >> 6, l = t & 63;
    const int wr = w >> 2, wc = w & 3;

    const int nwg = gridDim.x;
    const int bid = blockIdx.x;
    const int swz = (bid & 7) * (nwg >> 3) + (bid >> 3);
    const int cb = swz & 1;
    const int rgrp = swz >> 1;
    const int brow0 = rgrp * 256;
    const int bcol = cb << 8;

    const int kksw = (((t & 3) ^ ((t >> 3) & 3)) << 3);
    const size_t aTh = (size_t)(t >> 2) * KT + kksw;
    const size_t bTh = (size_t)(bcol + (t >> 2)) * KT + kksw;
    const ushort* const aPanel = A + (size_t)brow0 * KT;
    char* const dA = (char*)sm + (w << 10);
    char* const dB = dA + 65536;

    const int xorv = ((l >> 1) & 3) << 4;
    const int preA = ((((wr << 7) + (l & 15)) << 6) + ((l >> 4) << 4)) ^ xorv;
    const int preB = 65536 + (((((wc << 6) + (l & 15)) << 6) + ((l >> 4) << 4)) ^ xorv);

    f32x4 acc[8][4] = {};
    bf16x8 aF[4], bF[4];

    auto issueA = [&](int T, int kh) {
        const int slot = ((T & 1) << 1) | kh;
        const ushort* s = aPanel + aTh + T * 64 + kh * 32;
        char* d = dA + (slot << 14);
        __builtin_amdgcn_global_load_lds(GLOBAL_AS(s), LDS_AS(d), 16, 0, 0);
        __builtin_amdgcn_global_load_lds(GLOBAL_AS(s + (size_t)128 * KT), LDS_AS(d + 8192), 16, 0, 0);
    };
    auto issueB = [&](int T, int kh) {
        const int slot = ((T & 1) << 1) | kh;
        const ushort* s = Bt + bTh + T * 64 + kh * 32;
        char* d = dB + (slot << 14);
        __builtin_amdgcn_global_load_lds(GLOBAL_AS(s), LDS_AS(d), 16, 0, 0);
        __builtin_amdgcn_global_load_lds(GLOBAL_AS(s + (size_t)128 * KT), LDS_AS(d + 8192), 16, 0, 0);
    };
    auto rdA = [&](int slot, int mb) {
        const char* p = (const char*)sm + (slot << 14) + preA + (mb << 12);
        aF[0] = *(const bf16x8*)(p);
        aF[1] = *(const bf16x8*)(p + 1024);
        aF[2] = *(const bf16x8*)(p + 2048);
        aF[3] = *(const bf16x8*)(p + 3072);
    };
    auto rdB = [&](int slot) {
        const char* p = (const char*)sm + (slot << 14) + preB;
        bF[0] = *(const bf16x8*)(p);
        bF[1] = *(const bf16x8*)(p + 1024);
        bF[2] = *(const bf16x8*)(p + 2048);
        bF[3] = *(const bf16x8*)(p + 3072);
    };
    auto mfma16 = [&](int mb) {
        __builtin_amdgcn_s_setprio(1);
#pragma unroll
        for (int mf = 0; mf < 4; ++mf)
#pragma unroll
            for (int nf = 0; nf < 4; ++nf)
                acc[mb * 4 + mf][nf] = __builtin_amdgcn_mfma_f32_16x16x32_bf16(
                    aF[mf], bF[nf], acc[mb * 4 + mf][nf], 0, 0, 0);
        __builtin_amdgcn_s_setprio(0);
    };

    auto tile_body = [&](int T) {
        const int s0 = (T & 1) << 1;
        rdA(s0, 0); rdB(s0);
        if (T + 1 < TT) issueB(T + 1, 1);
        SBAR();
        mfma16(0);
        SBAR();
        rdA(s0, 1);
        if (T + 2 < TT) issueA(T + 2, 0);
        SBAR();
        mfma16(1);
        SBAR();
        rdA(s0 + 1, 0); rdB(s0 + 1);
        if (T + 2 < TT) issueB(T + 2, 0);
        SBAR();
        mfma16(0);
        SBAR();
        rdA(s0 + 1, 1);
        if (T + 2 < TT) issueA(T + 2, 1);
        SBAR();
        mfma16(1);
        __builtin_amdgcn_sched_barrier(0);
        if (T < TT - 2)       { asm volatile("s_waitcnt vmcnt(6)" ::: "memory"); }
        else if (T == TT - 2) { asm volatile("s_waitcnt vmcnt(0)" ::: "memory"); }
        SBAR();
    };

    issueA(0, 0); issueB(0, 0);
    issueA(0, 1); issueB(0, 1);
    issueA(1, 0); issueB(1, 0);
    issueA(1, 1);
    __builtin_amdgcn_sched_barrier(0);
    asm volatile("s_waitcnt vmcnt(6)" ::: "memory");
    SBAR();

#pragma unroll 1
    for (int T = 0; T < TT; ++T)
        tile_body(T);

    // epilogue: two 128-row f32 [128][256] LDS halves (lgkm-only barriers).
#pragma unroll
    for (int h2 = 0; h2 < 2; ++h2) {
        if (wr == h2) {
#pragma unroll
            for (int mf = 0; mf < 8; ++mf)
#pragma unroll
                for (int nf = 0; nf < 4; ++nf)
#pragma unroll
                    for (int r = 0; r < 4; ++r) {
                        int rl = mf * 16 + ((l >> 4) << 2) + r;
                        int col = (wc << 6) + nf * 16 + (l & 15);
                        *(float*)(sm + rl * 1024 + col * 4) = acc[mf][nf][r];
                    }
        }
        LBAR();
#pragma unroll
        for (int k = 0; k < 16; ++k) {
            int c = t + (k << 9);
            int row = c >> 6, c4 = c & 63;
            f32x4 v = *(const f32x4*)(sm + ((size_t)c << 4));
            int R = brow0 + (h2 << 7) + row;
            int col0 = bcol + (c4 << 2);
            f32x4 bb = *(const f32x4*)(bias + col0);
            f32x4 x0 = *(const f32x4*)(resid + (size_t)R * 512 + col0);
            f32x4 x1 = *(const f32x4*)(resid + (size_t)rolled_row(R) * 512 + col0);
            v = v + bb + x0 + x1;
            *(f32x4*)(outF + (size_t)R * N + col0) = v;
        }
        if (h2 == 0) LBAR();
    }
}

// ---------------------------------------------------------------------------
extern "C" void kernel_launch(void* const* d_in, const int* in_sizes, int n_in,
                              void* d_out, int out_size, void* d_ws, size_t ws_size,
                              hipStream_t stream) {
    const float* in = (const float*)d_in[0];
    const float* ln_g = (const float*)d_in[1];
    const float* ln_b = (const float*)d_in[2];
    const float* W1 = (const float*)d_in[3];
    const float* b1 = (const float*)d_in[4];
    const float* W2 = (const float*)d_in[5];
    const float* b2 = (const float*)d_in[6];
    float* out = (float*)d_out;

    char* ws = (char*)d_ws;
    ushort* normed = (ushort*)ws;                                  // 32 MB
    ushort* hbuf   = (ushort*)(ws + (size_t)32 * 1024 * 1024);     // 128 MB (k-permuted)
    ushort* W1T    = (ushort*)(ws + (size_t)160 * 1024 * 1024);    // 2 MB
    ushort* W2T    = (ushort*)(ws + (size_t)162 * 1024 * 1024);    // 2 MB (k-permuted)

    prep_kernel<<<dim3(18432), 256, 0, stream>>>(in, ln_g, ln_b, normed,
                                                 W1, W1T, W2, W2T);
    mlp_gemm1<<<dim3(4096), 256, 0, stream>>>(normed, W1T, b1, hbuf);
    mlp_gemm2<<<dim3(256), 512, 0, stream>>>(hbuf, W2T, b2, in, out);
}

// Round 23
// 189.136 us; speedup vs baseline: 1.4684x; 1.0178x over previous
//
#include <hip/hip_runtime.h>
#include <hip/hip_bf16.h>
#include <cstdint>
#include <cstddef>

// ---------------------------------------------------------------------------
// SwinWindowTransformLayer: roll+add -> LayerNorm -> MLP(GELU) -> +x
// Round 23: G2 ported into G1's proven structure (128x128 tile, BK=64,
// 2-barrier loop, conflict-free swizzle, 4 blocks/CU, XCD row-panel order).
// Rationale: G1 and G2 measured identical at equal FLOPs; G2's K=2048 gives
// 32 K-iters/tile (4x better prologue amortization than G1's 8). Epilogue =
// R1's proven direct-store form. prep/G1 frozen from R22.
// ---------------------------------------------------------------------------

typedef short bf16x8 __attribute__((ext_vector_type(8)));
typedef float f32x4 __attribute__((ext_vector_type(4)));

#define GLOBAL_AS(p) ((__attribute__((address_space(1))) void*)(uintptr_t)(p))
#define LDS_AS(p)    ((__attribute__((address_space(3))) void*)(p))

static __device__ __forceinline__ ushort f2bf(float f) {
    uint32_t u = __float_as_uint(f);
    uint32_t r = (u + 0x7FFFu + ((u >> 16) & 1u)) >> 16;
    return (ushort)r;
}

// tanh-gelu == v*sigmoid(v*(A+B v^2)); exp via v_exp_f32 (2^x), log2e folded.
static __device__ __forceinline__ float gelu_e2(float v) {
    float v2 = v * v;
    float m = fmaf(-0.1029433f, v2, -2.3022084f);
    float t = v * m;
    float e;
    asm("v_exp_f32 %0, %1" : "=v"(e) : "v"(t));
    return v * __builtin_amdgcn_rcpf(1.0f + e);
}

// roll by (-4,-4) on a 64x64 grid
static __device__ __forceinline__ int rolled_row(int row) {
    int b = row >> 12, n = row & 4095;
    int h = n >> 6, wv = n & 63;
    int n2 = (((h + 4) & 63) << 6) | ((wv + 4) & 63);
    return (b << 12) | n2;
}

// ---------------------------------------------------------------------------
// prep: blockIdx [0,16384) = LN (2 rows/block); [16384,17408) = W1 transpose;
// [17408,18432) = W2 transpose (k-permuted). 256 threads everywhere.
// ---------------------------------------------------------------------------
__global__ __launch_bounds__(256)
void prep_kernel(const float* __restrict__ in, const float* __restrict__ gamma,
                 const float* __restrict__ beta, ushort* __restrict__ normed,
                 const float* __restrict__ W1, ushort* __restrict__ W1T,
                 const float* __restrict__ W2, ushort* __restrict__ W2T) {
    const int bid = blockIdx.x;
    if (bid < 16384) {
        const int half = threadIdx.x >> 7;
        const int t = threadIdx.x & 127;
        const int wave = threadIdx.x >> 6;
        const int row = bid * 2 + half;
        const int row2 = rolled_row(row);

        const float4* p0 = (const float4*)(in + (size_t)row * 512);
        const float4* p1 = (const float4*)(in + (size_t)row2 * 512);
        float4 a = p0[t], c = p1[t];
        float x0 = a.x + c.x, x1 = a.y + c.y, x2 = a.z + c.z, x3 = a.w + c.w;

        float s = x0 + x1 + x2 + x3;
        float sq = x0 * x0 + x1 * x1 + x2 * x2 + x3 * x3;
#pragma unroll
        for (int o = 32; o > 0; o >>= 1) {
            s += __shfl_xor(s, o);
            sq += __shfl_xor(sq, o);
        }
        __shared__ float red[4][2];
        if ((threadIdx.x & 63) == 0) { red[wave][0] = s; red[wave][1] = sq; }
        __syncthreads();
        const int w0 = half * 2;
        s = red[w0][0] + red[w0 + 1][0];
        sq = red[w0][1] + red[w0 + 1][1];
        float mu = s * (1.0f / 512.0f);
        float var = sq * (1.0f / 512.0f) - mu * mu;
        float rs = rsqrtf(var + 1e-6f);

        float4 g = ((const float4*)gamma)[t];
        float4 be = ((const float4*)beta)[t];
        ushort4 o4;
        o4.x = f2bf((x0 - mu) * rs * g.x + be.x);
        o4.y = f2bf((x1 - mu) * rs * g.y + be.y);
        o4.z = f2bf((x2 - mu) * rs * g.z + be.z);
        o4.w = f2bf((x3 - mu) * rs * g.w + be.w);
        ((ushort4*)(normed + (size_t)row * 512))[t] = o4;
    } else {
        __shared__ float tile[32][33];
        const int tx = threadIdx.x & 31, ty = threadIdx.x >> 5;
        const bool isW2 = bid >= 17408;
        const int i = isW2 ? (bid - 17408) : (bid - 16384);
        const int NBX = isW2 ? 16 : 64;
        const int Ccols = isW2 ? 512 : 2048;
        const int R = isW2 ? 2048 : 512;
        const float* src = isW2 ? W2 : W1;
        ushort* dst = isW2 ? W2T : W1T;
        const int bx = (i % NBX) * 32;
        const int by = (i / NBX) * 32;
#pragma unroll
        for (int r = 0; r < 32; r += 8)
            tile[ty + r][tx] = src[(size_t)(by + ty + r) * Ccols + bx + tx];
        __syncthreads();
        int k = by + tx;
        int kd = isW2 ? ((k & ~63) | ((k & 15) << 2) | ((k >> 4) & 3)) : k;
#pragma unroll
        for (int r = 0; r < 32; r += 8)
            dst[(size_t)(bx + ty + r) * R + kd] = f2bf(tile[tx][ty + r]);
    }
}

// ---------------------------------------------------------------------------
// G1 (frozen from R22): h = bf16(gelu(normed @ W1 + b1)), k-permuted stores.
// 128x128 tile, BK=64, 2-barrier K-loop, conflict-free XOR swizzle, XCD
// row-panel order, (256,4).
// ---------------------------------------------------------------------------
__global__ __launch_bounds__(256, 4)
void mlp_gemm1(const ushort* __restrict__ A, const ushort* __restrict__ Bt,
               const float* __restrict__ bias, ushort* __restrict__ outH) {
    constexpr int K = 512, N = 2048, BK = 64;
    __shared__ ushort Asm[128 * BK];   // 16 KB
    __shared__ ushort Bsm[128 * BK];   // 16 KB

    const int t = threadIdx.x;
    const int w = t >> 6, l = t & 63;
    const int wr = w >> 1, wc = w & 1;

    const int bid = blockIdx.x;
    const int xcd = bid & 7, idx = bid >> 3;
    const int brow = ((xcd << 5) + (idx >> 4)) << 7;
    const int bcol = (idx & 15) << 7;

    f32x4 acc[4][4] = {};

    const int trow = t >> 3;
    const int csrc = (((t & 7) ^ ((t >> 3) & 7)) << 3);
    const size_t aBase = (size_t)(brow + trow) * K + csrc;
    const size_t bBase = (size_t)(bcol + trow) * K + csrc;
    char* const ldsA = (char*)Asm + w * 1024;
    char* const ldsB = (char*)Bsm + w * 1024;

    const int rA = l & 15;
    const int cb0 = ((l >> 4) ^ (rA & 7)) << 4;
    const int bA0 = (wr << 13) + (rA << 7) + cb0;
    const int bB0 = (wc << 13) + (rA << 7) + cb0;
    const char* const pA0 = (const char*)Asm + bA0;
    const char* const pA1 = (const char*)Asm + (bA0 ^ 64);
    const char* const pB0 = (const char*)Bsm + bB0;
    const char* const pB1 = (const char*)Bsm + (bB0 ^ 64);

    for (int k0 = 0; k0 < K; k0 += BK) {
#pragma unroll
        for (int i = 0; i < 4; ++i) {
            __builtin_amdgcn_global_load_lds(GLOBAL_AS(A + aBase + (size_t)(i * 32) * K + k0),
                                             LDS_AS(ldsA + i * 4096), 16, 0, 0);
            __builtin_amdgcn_global_load_lds(GLOBAL_AS(Bt + bBase + (size_t)(i * 32) * K + k0),
                                             LDS_AS(ldsB + i * 4096), 16, 0, 0);
        }
        __syncthreads();

#pragma unroll
        for (int s = 0; s < 2; ++s) {
            const char* pa = s ? pA1 : pA0;
            const char* pb = s ? pB1 : pB0;
            bf16x8 aF[4], bF[4];
#pragma unroll
            for (int i = 0; i < 4; ++i)
                aF[i] = *(const bf16x8*)(pa + i * 2048);
#pragma unroll
            for (int j = 0; j < 4; ++j)
                bF[j] = *(const bf16x8*)(pb + j * 2048);
#pragma unroll
            for (int i = 0; i < 4; ++i)
#pragma unroll
                for (int j = 0; j < 4; ++j)
                    acc[i][j] = __builtin_amdgcn_mfma_f32_16x16x32_bf16(aF[i], bF[j], acc[i][j], 0, 0, 0);
        }
        __syncthreads();
    }

    const int cm = (l >> 4) << 2;
    const int cn = l & 15;
    float bvv[4];
#pragma unroll
    for (int j = 0; j < 4; ++j)
        bvv[j] = bias[bcol + wc * 64 + j * 16 + cn];
    const int ecol = bcol + wc * 64 + (cn << 2);
#pragma unroll
    for (int i = 0; i < 4; ++i) {
#pragma unroll
        for (int r = 0; r < 4; ++r) {
            const int row = brow + wr * 64 + i * 16 + cm + r;
            float f0 = gelu_e2(acc[i][0][r] + bvv[0]);
            float f1 = gelu_e2(acc[i][1][r] + bvv[1]);
            float f2 = gelu_e2(acc[i][2][r] + bvv[2]);
            float f3 = gelu_e2(acc[i][3][r] + bvv[3]);
            uint32_t lo, hi;
            asm("v_cvt_pk_bf16_f32 %0, %1, %2" : "=v"(lo) : "v"(f0), "v"(f1));
            asm("v_cvt_pk_bf16_f32 %0, %1, %2" : "=v"(hi) : "v"(f2), "v"(f3));
            uint2 pv; pv.x = lo; pv.y = hi;
            *(uint2*)(outH + (size_t)row * N + ecol) = pv;
        }
    }
}

// ---------------------------------------------------------------------------
// G2': out = hbuf @ W2 + b2 + resid[row] + resid[roll(row)] -- in the G1
// structure. 128x128 tile, BK=64 (32 K-iters), 4 blocks/CU, conflict-free
// swizzle, XCD row-panel order (32 row-panels x 4 col-blocks per XCD).
// Both operands k-permuted identically (sum order irrelevant).
// ---------------------------------------------------------------------------
__global__ __launch_bounds__(256, 4)
void mlp_gemm2(const ushort* __restrict__ A, const ushort* __restrict__ Bt,
               const float* __restrict__ bias, const float* __restrict__ resid,
               float* __restrict__ outF) {
    constexpr int K = 2048, N = 512, BK = 64;
    __shared__ ushort Asm[128 * BK];   // 16 KB
    __shared__ ushort Bsm[128 * BK];   // 16 KB

    const int t = threadIdx.x;
    const int w = t >> 6, l = t & 63;
    const int wr = w >> 1, wc = w & 1;

    const int bid = blockIdx.x;
    const int xcd = bid & 7, idx = bid >> 3;   // idx in [0,128)
    const int brow = ((xcd << 5) + (idx >> 2)) << 7;   // 32 row-panels/XCD
    const int bcol = (idx & 3) << 7;                   // 4 col-blocks

    f32x4 acc[4][4] = {};

    const int trow = t >> 3;
    const int csrc = (((t & 7) ^ ((t >> 3) & 7)) << 3);
    const size_t aBase = (size_t)(brow + trow) * K + csrc;
    const size_t bBase = (size_t)(bcol + trow) * K + csrc;
    char* const ldsA = (char*)Asm + w * 1024;
    char* const ldsB = (char*)Bsm + w * 1024;

    const int rA = l & 15;
    const int cb0 = ((l >> 4) ^ (rA & 7)) << 4;
    const int bA0 = (wr << 13) + (rA << 7) + cb0;
    const int bB0 = (wc << 13) + (rA << 7) + cb0;
    const char* const pA0 = (const char*)Asm + bA0;
    const char* const pA1 = (const char*)Asm + (bA0 ^ 64);
    const char* const pB0 = (const char*)Bsm + bB0;
    const char* const pB1 = (const char*)Bsm + (bB0 ^ 64);

    for (int k0 = 0; k0 < K; k0 += BK) {
#pragma unroll
        for (int i = 0; i < 4; ++i) {
            __builtin_amdgcn_global_load_lds(GLOBAL_AS(A + aBase + (size_t)(i * 32) * K + k0),
                                             LDS_AS(ldsA + i * 4096), 16, 0, 0);
            __builtin_amdgcn_global_load_lds(GLOBAL_AS(Bt + bBase + (size_t)(i * 32) * K + k0),
                                             LDS_AS(ldsB + i * 4096), 16, 0, 0);
        }
        __syncthreads();

#pragma unroll
        for (int s = 0; s < 2; ++s) {
            const char* pa = s ? pA1 : pA0;
            const char* pb = s ? pB1 : pB0;
            bf16x8 aF[4], bF[4];
#pragma unroll
            for (int i = 0; i < 4; ++i)
                aF[i] = *(const bf16x8*)(pa + i * 2048);
#pragma unroll
            for (int j = 0; j < 4; ++j)
                bF[j] = *(const bf16x8*)(pb + j * 2048);
#pragma unroll
            for (int i = 0; i < 4; ++i)
#pragma unroll
                for (int j = 0; j < 4; ++j)
                    acc[i][j] = __builtin_amdgcn_mfma_f32_16x16x32_bf16(aF[i], bF[j], acc[i][j], 0, 0, 0);
        }
        __syncthreads();
    }

    // epilogue (R1-proven form): bias + both residual gathers, f32 stores.
    // Per (i,r): 16 lanes x 4B = 64B contiguous segments per j.
    const int cm = (l >> 4) << 2;
    const int cn = l & 15;
    float bvv[4];
#pragma unroll
    for (int j = 0; j < 4; ++j)
        bvv[j] = bias[bcol + wc * 64 + j * 16 + cn];
#pragma unroll
    for (int i = 0; i < 4; ++i) {
#pragma unroll
        for (int r = 0; r < 4; ++r) {
            const int row = brow + wr * 64 + i * 16 + cm + r;
            const float* x0 = resid + (size_t)row * 512;
            const float* x1 = resid + (size_t)rolled_row(row) * 512;
#pragma unroll
            for (int j = 0; j < 4; ++j) {
                const int col = bcol + wc * 64 + j * 16 + cn;
                outF[(size_t)row * N + col] = acc[i][j][r] + bvv[j] + x0[col] + x1[col];
            }
        }
    }
}

// ---------------------------------------------------------------------------
extern "C" void kernel_launch(void* const* d_in, const int* in_sizes, int n_in,
                              void* d_out, int out_size, void* d_ws, size_t ws_size,
                              hipStream_t stream) {
    const float* in = (const float*)d_in[0];
    const float* ln_g = (const float*)d_in[1];
    const float* ln_b = (const float*)d_in[2];
    const float* W1 = (const float*)d_in[3];
    const float* b1 = (const float*)d_in[4];
    const float* W2 = (const float*)d_in[5];
    const float* b2 = (const float*)d_in[6];
    float* out = (float*)d_out;

    char* ws = (char*)d_ws;
    ushort* normed = (ushort*)ws;                                  // 32 MB
    ushort* hbuf   = (ushort*)(ws + (size_t)32 * 1024 * 1024);     // 128 MB (k-permuted)
    ushort* W1T    = (ushort*)(ws + (size_t)160 * 1024 * 1024);    // 2 MB
    ushort* W2T    = (ushort*)(ws + (size_t)162 * 1024 * 1024);    // 2 MB (k-permuted)

    prep_kernel<<<dim3(18432), 256, 0, stream>>>(in, ln_g, ln_b, normed,
                                                 W1, W1T, W2, W2T);
    mlp_gemm1<<<dim3(4096), 256, 0, stream>>>(normed, W1T, b1, hbuf);
    // G2': [32768,2048]x[2048,512] + bias + x -> out, 1024 blocks (4/CU)
    mlp_gemm2<<<dim3(1024), 256, 0, stream>>>(hbuf, W2T, b2, in, out);
}